// Round 8
// baseline (764.989 us; speedup 1.0000x reference)
//
#include <hip/hip_runtime.h>
#include <math.h>

typedef __attribute__((ext_vector_type(8))) _Float16 f16x8;
typedef __attribute__((ext_vector_type(4))) _Float16 f16x4;
typedef __attribute__((ext_vector_type(4))) float f32x4;

// ---------------------------------------------------------------------------
// Precision: split-fp16 planes a = ah + al/2048 (al stored x2048).
// C = ah@wh + (ah@wl_s + al_s@wh)/2048 -> ~2^-22 rel (fp32-grade); the final
// pos/(|pos|+1e-8) amplifies error ~1e4 -> budget ~2^-20, no compression.
//
// Round 8: (a) aggregate loads 64 CSR indices per wave in one coalesced
// vector load + __shfl broadcast (kills the scalar-load->gather serial
// chain; 4 independent acc chains). (b) GEMM ROWS=64/MT=4: halves B
// re-reads, 36 MFMA per 6 B-loads per wave-slab; all-A staged once (48 KB),
// one barrier, barrier-free K-loop.
//
// Packed activation layout (x, h, p1), "block-packed split-fp16":
//   32-row pages: chunk16B(r,p) at ((rb32*NS+s)*32 + r)*128 + p*16,
//   p = c ^ (r&7); c<4: hi-plane k-octet c; c>=4: lo-plane octet (c-4).
//   Global image == LDS image; staging is a pure contiguous DMA.
//   Packed buffers sized for 2*ceil(M/64) 32-row pages (64-row blocks read
//   full pages; garbage rows masked in epilogue).
// ---------------------------------------------------------------------------

// ------------------------- graph setup -------------------------------------
__global__ void count_kernel(const int* __restrict__ dst, int E, int* __restrict__ cnt) {
    int i = blockIdx.x * blockDim.x + threadIdx.x;
    if (i < E) atomicAdd(&cnt[dst[i]], 1);
}

__global__ void scan1_kernel(const int* __restrict__ cnt, int M,
                             int* __restrict__ rowptr, int* __restrict__ bsum,
                             float* __restrict__ dinv) {
    __shared__ int s[256];
    int t = threadIdx.x;
    int i = blockIdx.x * 256 + t;
    int v = (i < M) ? cnt[i] : 0;
    s[t] = v; __syncthreads();
    for (int o = 1; o < 256; o <<= 1) {
        int x = (t >= o) ? s[t - o] : 0;
        __syncthreads();
        s[t] += x;
        __syncthreads();
    }
    if (i < M) {
        rowptr[i] = s[t] - v;
        dinv[i] = rsqrtf((float)v + 1.0f);  // deg = in-deg + self-loop
    }
    if (t == 255) bsum[blockIdx.x] = s[255];
}

__global__ void scan2_kernel(const int* __restrict__ bsum, int nb, int* __restrict__ boff) {
    __shared__ int s[256];
    int t = threadIdx.x;
    int v = (t < nb) ? bsum[t] : 0;
    s[t] = v; __syncthreads();
    for (int o = 1; o < 256; o <<= 1) {
        int x = (t >= o) ? s[t - o] : 0;
        __syncthreads();
        s[t] += x;
        __syncthreads();
    }
    if (t < nb) boff[t] = s[t] - v;
}

__global__ void scan3_kernel(int* __restrict__ rowptr, int M, int E, const int* __restrict__ boff) {
    int i = blockIdx.x * 256 + threadIdx.x;
    if (i < M) rowptr[i] += boff[blockIdx.x];
    if (i == M) rowptr[M] = E;
}

__global__ void fill_kernel(const int* __restrict__ src, const int* __restrict__ dst, int E,
                            const int* __restrict__ rowptr, int* __restrict__ cursor,
                            int* __restrict__ csr) {
    int i = blockIdx.x * blockDim.x + threadIdx.x;
    if (i < E) {
        int d = dst[i];
        int slot = atomicAdd(&cursor[d], 1);
        csr[rowptr[d] + slot] = src[i];
    }
}

// ------------------------- converters --------------------------------------
// x -> block-packed split planes (4 slabs). One 16-B chunk per thread.
__global__ void convert_x_kernel(const float* __restrict__ x, _Float16* __restrict__ xp,
                                 int M, int nchunks) {
    int g = blockIdx.x * 256 + threadIdx.x;
    if (g >= nchunks) return;
    int p = g & 7;
    int t1 = g >> 3;
    int r = t1 & 31;
    int t2 = t1 >> 5;
    int s = t2 & 3;
    int rb = t2 >> 2;
    int c = p ^ (r & 7);
    int node = rb * 32 + r;
    int k = s * 32 + (c & 3) * 8;
    f16x8 o = {};
    if (node < M) {
        const float* xr = x + (size_t)node * 128 + k;
#pragma unroll
        for (int j = 0; j < 8; ++j) {
            float v = xr[j];
            _Float16 hi = (_Float16)v;
            o[j] = (c < 4) ? hi : (_Float16)((v - (float)hi) * 2048.f);
        }
    }
    reinterpret_cast<f16x8*>(xp)[g] = o;
}

// Frag-major B packing: flat i = ((s*G + g)*64 + l)*8 + j, G=N/16;
// value = W[k][n], n = g*16 + (l&15), k = s*32 + (l>>4)*8 + j.
struct WSeg { const float* src; _Float16* dh; _Float16* dl; int K; int N; };
struct WSegs { WSeg s[8]; };

__global__ void pack_b_kernel(WSegs segs) {
    WSeg sg = segs.s[blockIdx.y];
    int i = blockIdx.x * 256 + threadIdx.x;
    if (i >= sg.K * sg.N) return;
    int G = sg.N >> 4;
    int s = i / (G * 512);
    int r = i - s * (G * 512);
    int g = r >> 9;
    int r2 = r & 511;
    int l = r2 >> 3, j = r2 & 7;
    int n = g * 16 + (l & 15);
    int k = s * 32 + (l >> 4) * 8 + j;
    float w = sg.src[(size_t)k * sg.N + n];
    _Float16 hi = (_Float16)w;
    sg.dh[i] = hi;
    sg.dl[i] = (_Float16)((w - (float)hi) * 2048.f);
}

// --------------------- global->LDS 16B helper -------------------------------
__device__ __forceinline__ void gload_lds16(const _Float16* src, char* dst_wavebase) {
#if __has_builtin(__builtin_amdgcn_global_load_lds)
    __builtin_amdgcn_global_load_lds(
        (const __attribute__((address_space(1))) void*)src,
        (__attribute__((address_space(3))) void*)dst_wavebase, 16, 0, 0);
#else
    *reinterpret_cast<f16x8*>(dst_wavebase + (threadIdx.x & 63) * 16) =
        *reinterpret_cast<const f16x8*>(src);
#endif
}

// ---------------------------------------------------------------------------
// Split-fp16 MFMA GEMM, ROWS=64, all-A staged (NS*8 KB <= 48 KB), one
// barrier, barrier-free K-loop; B frag-major from global (L2-hot).
//   NN=192: MT=4, wave w -> rows 0-63, cols [w*48,+48): 36 MFMA / 6 B-loads
//   NN=96 : MT=2, wave w -> rows [(w>>1)*32,+32), cols [(w&1)*48,+48)
// OM bit0: fp32 row-major out Cf. OM bit1: block-packed split out Cp.
// ---------------------------------------------------------------------------
template <int KK, int NN, int ACT, int OM>
__global__ __launch_bounds__(256, 2) void mfma_gemm(
    const _Float16* __restrict__ Ap,
    const _Float16* __restrict__ Bph, const _Float16* __restrict__ Bpl,
    const float* __restrict__ bias, const float* __restrict__ rowscale,
    float* __restrict__ Cf, _Float16* __restrict__ Cp, int M) {
    constexpr int NS = KK / 32;
    constexpr int G = NN / 16;
    constexpr int MT = (NN == 192) ? 4 : 2;
    constexpr int NSO = NN / 32;
    __shared__ __align__(16) char smem[NS * 8192];

    const int tid = threadIdx.x;
    const int wave = tid >> 6, lane = tid & 63;
    const int quad = lane >> 4, l16 = lane & 15;
    const int m0 = (NN == 192) ? 0 : (wave >> 1) * 32;
    const int n0 = (NN == 192) ? wave * 48 : (wave & 1) * 48;
    const int g0 = n0 >> 4;
    const int row0 = blockIdx.x * 64;
    const int wb = (tid & ~63) * 16;

    // stage the whole 64-row A tile (two 32-row pages per slab), sync once
#pragma unroll
    for (int s = 0; s < NS; ++s)
#pragma unroll
        for (int half = 0; half < 2; ++half) {
            const _Float16* src =
                Ap + ((size_t)(2 * blockIdx.x + half) * NS + s) * 2048 + tid * 8;
            gload_lds16(src, smem + (s * 2 + half) * 4096 + wb);
        }

    f32x4 acc[MT][3], acc2[MT][3];
#pragma unroll
    for (int mt = 0; mt < MT; ++mt)
#pragma unroll
        for (int nt = 0; nt < 3; ++nt) {
            acc[mt][nt] = (f32x4){0.f, 0.f, 0.f, 0.f};
            acc2[mt][nt] = (f32x4){0.f, 0.f, 0.f, 0.f};
        }

    __syncthreads();  // the ONLY barrier

#pragma unroll
    for (int s = 0; s < NS; ++s) {
        f16x8 bh[3], bl[3];
#pragma unroll
        for (int nt = 0; nt < 3; ++nt) {
            size_t o = ((size_t)(s * G + g0 + nt) * 64 + lane) * 8;
            bh[nt] = *reinterpret_cast<const f16x8*>(Bph + o);
            bl[nt] = *reinterpret_cast<const f16x8*>(Bpl + o);
        }
        const char* As = smem + s * 8192;
        f16x8 ah[MT], al[MT];
#pragma unroll
        for (int mt = 0; mt < MT; ++mt) {
            int R = m0 + mt * 16 + l16;
            int ph = quad ^ (R & 7);
            const char* rbase = As + (R >> 5) * 4096 + (R & 31) * 128;
            ah[mt] = *reinterpret_cast<const f16x8*>(rbase + ph * 16);
            al[mt] = *reinterpret_cast<const f16x8*>(rbase + (ph ^ 4) * 16);
        }
#pragma unroll
        for (int mt = 0; mt < MT; ++mt)
#pragma unroll
            for (int nt = 0; nt < 3; ++nt) {
                acc[mt][nt] = __builtin_amdgcn_mfma_f32_16x16x32_f16(ah[mt], bh[nt], acc[mt][nt], 0, 0, 0);
                acc2[mt][nt] = __builtin_amdgcn_mfma_f32_16x16x32_f16(ah[mt], bl[nt], acc2[mt][nt], 0, 0, 0);
                acc2[mt][nt] = __builtin_amdgcn_mfma_f32_16x16x32_f16(al[mt], bh[nt], acc2[mt][nt], 0, 0, 0);
            }
    }

    // epilogue: C/D layout col=lane&15, row=quad*4+reg
    float bv[3];
#pragma unroll
    for (int nt = 0; nt < 3; ++nt) bv[nt] = bias ? bias[n0 + nt * 16 + l16] : 0.f;
#pragma unroll
    for (int mt = 0; mt < MT; ++mt)
#pragma unroll
        for (int i = 0; i < 4; ++i) {
            int row = row0 + m0 + mt * 16 + quad * 4 + i;
            if (row < M) {
                float rs = rowscale ? rowscale[row] : 1.f;
#pragma unroll
                for (int nt = 0; nt < 3; ++nt) {
                    int col = n0 + nt * 16 + l16;
                    float v = acc[mt][nt][i] + acc2[mt][nt][i] * (1.f / 2048.f) + bv[nt];
                    if (ACT == 1) v = fmaxf(v, 0.f);
                    v *= rs;
                    if (OM & 1) Cf[(size_t)row * NN + col] = v;
                    if (OM & 2) {
                        _Float16 hi = (_Float16)v;
                        _Float16 lo = (_Float16)((v - (float)hi) * 2048.f);
                        int r = row & 31;
                        int os = col >> 5, oc = (col >> 3) & 3, j = col & 7;
                        size_t base = ((size_t)((row >> 5) * NSO + os) * 32 + r) * 64;
                        int ph2 = oc ^ (r & 7);
                        Cp[base + ph2 * 8 + j] = hi;
                        Cp[base + (ph2 ^ 4) * 8 + j] = lo;
                    }
                }
            }
        }
}

// ---------------------------------------------------------------------------
// fp32 aggregation, shfl-broadcast indices. One wave per node.
// Indices for up to 64 edges loaded in ONE coalesced vector load, broadcast
// via __shfl; 4 independent accumulator chains for MLP.
// h = h + relu(dinv[n]*(msc[n] + sum_e msc[src_e]) + B); h block-packed.
// ---------------------------------------------------------------------------
__global__ __launch_bounds__(256) void aggregate_kernel(
    const float* __restrict__ msc, const int* __restrict__ csr,
    const int* __restrict__ rowptr, const float* __restrict__ dinv,
    const float* __restrict__ bias, _Float16* __restrict__ h, int M) {
    int wid = (blockIdx.x * 256 + threadIdx.x) >> 6;
    int lane = threadIdx.x & 63;
    if (wid >= M) return;
    const bool act = lane < 48;
    const float4* m4 = reinterpret_cast<const float4*>(msc);

    float4 a0 = make_float4(0.f, 0.f, 0.f, 0.f), a1 = a0, a2 = a0, a3 = a0;
    if (act) a0 = m4[(size_t)wid * 48 + lane];  // self-loop (already * dinv[wid])
    const int beg = rowptr[wid], end = rowptr[wid + 1];

    for (int b = beg; b < end; b += 64) {
        const int cnt = min(64, end - b);
        int myidx = (lane < cnt) ? csr[b + lane] : 0;  // one coalesced load
        int j = 0;
        for (; j + 4 <= cnt; j += 4) {
            int i0 = __shfl(myidx, j, 64);
            int i1 = __shfl(myidx, j + 1, 64);
            int i2 = __shfl(myidx, j + 2, 64);
            int i3 = __shfl(myidx, j + 3, 64);
            if (act) {
                float4 v0 = m4[(size_t)i0 * 48 + lane];
                float4 v1 = m4[(size_t)i1 * 48 + lane];
                float4 v2 = m4[(size_t)i2 * 48 + lane];
                float4 v3 = m4[(size_t)i3 * 48 + lane];
                a0.x += v0.x; a0.y += v0.y; a0.z += v0.z; a0.w += v0.w;
                a1.x += v1.x; a1.y += v1.y; a1.z += v1.z; a1.w += v1.w;
                a2.x += v2.x; a2.y += v2.y; a2.z += v2.z; a2.w += v2.w;
                a3.x += v3.x; a3.y += v3.y; a3.z += v3.z; a3.w += v3.w;
            }
        }
        for (; j < cnt; ++j) {
            int i0 = __shfl(myidx, j, 64);
            if (act) {
                float4 v = m4[(size_t)i0 * 48 + lane];
                a0.x += v.x; a0.y += v.y; a0.z += v.z; a0.w += v.w;
            }
        }
    }
    if (!act) return;
    a0.x += a1.x + a2.x + a3.x;
    a0.y += a1.y + a2.y + a3.y;
    a0.z += a1.z + a2.z + a3.z;
    a0.w += a1.w + a2.w + a3.w;

    float dn = dinv[wid];
    float4 b = reinterpret_cast<const float4*>(bias)[lane];
    // packed-h address for features f0 = lane*4 .. +4
    int f0 = lane * 4;
    int s = f0 >> 5, c = (f0 >> 3) & 3, jh = (f0 >> 2) & 1;
    int r = wid & 31;
    size_t pbase = ((size_t)((wid >> 5) * 6 + s) * 32 + r) * 64;
    int ph = c ^ (r & 7);
    f16x4* hp = reinterpret_cast<f16x4*>(h + pbase + ph * 8 + jh * 4);
    f16x4* lp = reinterpret_cast<f16x4*>(h + pbase + (ph ^ 4) * 8 + jh * 4);
    f16x4 hh = *hp, hl = *lp;
    float4 hv;
    hv.x = (float)hh[0] + (float)hl[0] * (1.f / 2048.f) + fmaxf(a0.x * dn + b.x, 0.f);
    hv.y = (float)hh[1] + (float)hl[1] * (1.f / 2048.f) + fmaxf(a0.y * dn + b.y, 0.f);
    hv.z = (float)hh[2] + (float)hl[2] * (1.f / 2048.f) + fmaxf(a0.z * dn + b.z, 0.f);
    hv.w = (float)hh[3] + (float)hl[3] * (1.f / 2048.f) + fmaxf(a0.w * dn + b.w, 0.f);
    f16x4 nh = {(_Float16)hv.x, (_Float16)hv.y, (_Float16)hv.z, (_Float16)hv.w};
    f16x4 nl = {(_Float16)((hv.x - (float)nh[0]) * 2048.f),
                (_Float16)((hv.y - (float)nh[1]) * 2048.f),
                (_Float16)((hv.z - (float)nh[2]) * 2048.f),
                (_Float16)((hv.w - (float)nh[3]) * 2048.f)};
    *hp = nh;
    *lp = nl;
}

// ---------------------------------------------------------------------------
// Tail: pos = p2@Wp3+bp3; rad = sigmoid(r@Wr2+br2); out = pos/(|pos|+1e-8)*rad
// ---------------------------------------------------------------------------
__global__ void finalize_kernel(const float* __restrict__ p2, const float* __restrict__ rbuf,
                                const float* __restrict__ Wp3, const float* __restrict__ bp3,
                                const float* __restrict__ Wr2, const float* __restrict__ br2,
                                float* __restrict__ out, int M) {
    int n = blockIdx.x * 256 + threadIdx.x;
    if (n >= M) return;
    const float4* p = reinterpret_cast<const float4*>(p2 + (size_t)n * 96);
    const float4* r = reinterpret_cast<const float4*>(rbuf + (size_t)n * 96);
    float a0 = 0.f, a1 = 0.f, rr = 0.f;
#pragma unroll
    for (int q = 0; q < 24; q++) {
        float4 pv = p[q];
        float4 rv = r[q];
        float4 w01 = reinterpret_cast<const float4*>(Wp3)[2 * q];
        float4 w23 = reinterpret_cast<const float4*>(Wp3)[2 * q + 1];
        a0 += pv.x * w01.x + pv.y * w01.z + pv.z * w23.x + pv.w * w23.z;
        a1 += pv.x * w01.y + pv.y * w01.w + pv.z * w23.y + pv.w * w23.w;
        float4 wr = reinterpret_cast<const float4*>(Wr2)[q];
        rr += rv.x * wr.x + rv.y * wr.y + rv.z * wr.z + rv.w * wr.w;
    }
    a0 += bp3[0];
    a1 += bp3[1];
    rr += br2[0];
    float radius = 1.f / (1.f + expf(-rr));
    float nrm = sqrtf(a0 * a0 + a1 * a1) + 1e-8f;
    float s = radius / nrm;
    out[(size_t)n * 2 + 0] = a0 * s;
    out[(size_t)n * 2 + 1] = a1 * s;
}

extern "C" void kernel_launch(void* const* d_in, const int* in_sizes, int n_in,
                              void* d_out, int out_size, void* d_ws, size_t ws_size,
                              hipStream_t stream) {
    const float* x     = (const float*)d_in[0];
    const int*   ei    = (const int*)d_in[1];
    const float* Wp    = (const float*)d_in[2];
    const float* bp    = (const float*)d_in[3];
    const float* convW = (const float*)d_in[4];
    const float* convB = (const float*)d_in[5];
    const float* Wp1   = (const float*)d_in[6];
    const float* bp1   = (const float*)d_in[7];
    const float* Wp2   = (const float*)d_in[8];
    const float* bp2   = (const float*)d_in[9];
    const float* Wp3   = (const float*)d_in[10];
    const float* bp3   = (const float*)d_in[11];
    const float* Wr1   = (const float*)d_in[12];
    const float* br1   = (const float*)d_in[13];
    const float* Wr2   = (const float*)d_in[14];
    const float* br2   = (const float*)d_in[15];
    float* out = (float*)d_out;

    const int M = in_sizes[0] / 128;  // 50000
    const int E = in_sizes[1] / 2;    // 800000
    const int* srcI = ei;
    const int* dstI = ei + E;
    const int RB64 = (M + 63) / 64;   // 782 64-row GEMM blocks
    const int RBp  = RB64 * 2;        // 1564 32-row packed pages per slab set

    char* w = (char*)d_ws;
    size_t off = 0;
    auto alloc = [&](size_t b) { size_t o = off; off += (b + 255) & ~(size_t)255; return o; };
    float*    msc  = (float*)(w + alloc((size_t)RBp * 6 * 4096));    // fp32 msc / p1 packed
    _Float16* hpk  = (_Float16*)(w + alloc((size_t)RBp * 6 * 4096)); // h packed
    char*     xreg = w + alloc((size_t)RBp * 4 * 4096);  // x packed; later p2 fp32
    float*    rb_  = (float*)(w + alloc((size_t)M * 96 * 4));
    _Float16* WpPh  = (_Float16*)(w + alloc((size_t)128 * 192 * 2));
    _Float16* WpPl  = (_Float16*)(w + alloc((size_t)128 * 192 * 2));
    _Float16* cWPh  = (_Float16*)(w + alloc((size_t)4 * 192 * 192 * 2));
    _Float16* cWPl  = (_Float16*)(w + alloc((size_t)4 * 192 * 192 * 2));
    _Float16* Wp1Ph = (_Float16*)(w + alloc((size_t)192 * 192 * 2));
    _Float16* Wp1Pl = (_Float16*)(w + alloc((size_t)192 * 192 * 2));
    _Float16* Wp2Ph = (_Float16*)(w + alloc((size_t)192 * 96 * 2));
    _Float16* Wp2Pl = (_Float16*)(w + alloc((size_t)192 * 96 * 2));
    _Float16* Wr1Ph = (_Float16*)(w + alloc((size_t)192 * 96 * 2));
    _Float16* Wr1Pl = (_Float16*)(w + alloc((size_t)192 * 96 * 2));
    int*      cnt    = (int*)(w + alloc((size_t)M * 4));
    int*      cursor = (int*)(w + alloc((size_t)M * 4));
    float*    dinv   = (float*)(w + alloc((size_t)M * 4));
    int*      rowptr = (int*)(w + alloc((size_t)(M + 1) * 4));
    int*      csr    = (int*)(w + alloc((size_t)(E + 64) * 4));
    int*      bsum   = (int*)(w + alloc(256 * 4));
    int*      boff   = (int*)(w + alloc(256 * 4));

    _Float16* xpk  = (_Float16*)xreg;       // x packed (4 slabs)
    float*    p2   = (float*)xreg;          // alias: x packed dead after proj
    _Float16* p1pk = (_Float16*)msc;        // alias: msc dead after last aggregate

    // one memset covers cnt + cursor (adjacent allocs)
    hipMemsetAsync(cnt, 0, (size_t)((char*)cursor - (char*)cnt) + (size_t)M * 4, stream);

    // graph setup
    count_kernel<<<(E + 255) / 256, 256, 0, stream>>>(dstI, E, cnt);
    int nb = (M + 255) / 256;
    scan1_kernel<<<nb, 256, 0, stream>>>(cnt, M, rowptr, bsum, dinv);
    scan2_kernel<<<1, 256, 0, stream>>>(bsum, nb, boff);
    scan3_kernel<<<(M + 256) / 256, 256, 0, stream>>>(rowptr, M, E, boff);
    fill_kernel<<<(E + 255) / 256, 256, 0, stream>>>(srcI, dstI, E, rowptr, cursor, csr);

    // conversions
    int xchunks = RBp * 4 * 256;
    convert_x_kernel<<<(xchunks + 255) / 256, 256, 0, stream>>>(x, xpk, M, xchunks);
    WSegs segs;
    segs.s[0] = {Wp, WpPh, WpPl, 128, 192};
    segs.s[1] = {convW + 0 * 192 * 192, cWPh + 0 * 192 * 192, cWPl + 0 * 192 * 192, 192, 192};
    segs.s[2] = {convW + 1 * 192 * 192, cWPh + 1 * 192 * 192, cWPl + 1 * 192 * 192, 192, 192};
    segs.s[3] = {convW + 2 * 192 * 192, cWPh + 2 * 192 * 192, cWPl + 2 * 192 * 192, 192, 192};
    segs.s[4] = {convW + 3 * 192 * 192, cWPh + 3 * 192 * 192, cWPl + 3 * 192 * 192, 192, 192};
    segs.s[5] = {Wp1, Wp1Ph, Wp1Pl, 192, 192};
    segs.s[6] = {Wp2, Wp2Ph, Wp2Pl, 192, 96};
    segs.s[7] = {Wr1, Wr1Ph, Wr1Pl, 192, 96};
    pack_b_kernel<<<dim3(144, 8), 256, 0, stream>>>(segs);

    // h = x @ Wp + bp -> packed planes
    mfma_gemm<128, 192, 0, 2><<<RB64, 256, 0, stream>>>(
        xpk, WpPh, WpPl, bp, nullptr, nullptr, hpk, M);
    // 4 GCN layers
    for (int i = 0; i < 4; i++) {
        mfma_gemm<192, 192, 0, 1><<<RB64, 256, 0, stream>>>(
            hpk, cWPh + (size_t)i * 192 * 192, cWPl + (size_t)i * 192 * 192,
            nullptr, dinv, msc, nullptr, M);
        aggregate_kernel<<<(M + 3) / 4, 256, 0, stream>>>(
            msc, csr, rowptr, dinv, convB + (size_t)i * 192, hpk, M);
    }
    // heads
    mfma_gemm<192, 192, 1, 2><<<RB64, 256, 0, stream>>>(
        hpk, Wp1Ph, Wp1Pl, bp1, nullptr, nullptr, p1pk, M);
    mfma_gemm<192, 96, 1, 1><<<RB64, 256, 0, stream>>>(
        p1pk, Wp2Ph, Wp2Pl, bp2, nullptr, p2, nullptr, M);
    mfma_gemm<192, 96, 1, 1><<<RB64, 256, 0, stream>>>(
        hpk, Wr1Ph, Wr1Pl, br1, nullptr, rb_, nullptr, M);
    finalize_kernel<<<(M + 255) / 256, 256, 0, stream>>>(p2, rb_, Wp3, bp3, Wr2, br2, out, M);
}